// Round 7
// baseline (259.444 us; speedup 1.0000x reference)
//
#include <hip/hip_runtime.h>

// RIIDModelLSTM: 2-layer LSTM (H=6), T=512, B=8192, fused FC(6->32->1) head.
//
// v7: 16-lane gate-split, DPP-only, REGISTER-LIGHT.
// R4-R6 lesson: the 8-lane mapping needs ~180 live VGPRs; the allocator caps
// at 132 and services the overflow with remat/AGPR traffic (~250-300 cyc/step
// of invisible issue tax). Fix by mapping: 16 lanes/seq halves per-lane
// weights (48 floats), total live ~115 regs -> fits. Bonus: 2048 waves =
// 2 waves/SIMD -> dependency stalls hidden by the co-resident wave.
//
// Layout per 16-lane row (= 1 sequence; 4 seqs/wave):
//   l = L&15; half = l>>3 (0: gates [i,f], 1: gates [g,o]); k = l&7 (unit,
//   k=6,7 pad with zero weights). Unit k lives on lanes k and k+8.
//   Unified activation f(x) = 1 - B*rcp(1+2^(S*x)): sigmoid (B=1,S=L2E),
//   tanh (B=2,S=2*L2E); S folded into pre-scaled weights (R2-validated).
// Cross-lane (all DPP, no LDS):
//   gate swap: row_ror:8 (half0 <-> half1, same unit)
//   h gather:  row_ror:12 + 2 cndmask + quad bcasts -> h[0..5] unit-ordered
//   FC reduce: rotate-adds ror:1,2,4,8 over the 16-lane row
// FC head: rows 2l, 2l+1 per lane (32 rows over 16 lanes).

typedef float v2f __attribute__((ext_vector_type(2)));

static constexpr float L2E  = 1.44269504088896340736f;
static constexpr float TL2E = 2.0f * L2E;

#define DPP_QP(a,b,c,d) ((a)|((b)<<2)|((c)<<4)|((d)<<6))
#define DPP_B0  DPP_QP(0,0,0,0)   // quad bcast lane0
#define DPP_B1  DPP_QP(1,1,1,1)
#define DPP_B2  DPP_QP(2,2,2,2)
#define DPP_B3  DPP_QP(3,3,3,3)
#define DPP_R1  0x121             // row_ror:1
#define DPP_R2  0x122             // row_ror:2
#define DPP_R4  0x124             // row_ror:4
#define DPP_R8  0x128             // row_ror:8  (= lane xor 8 in 16-row)
#define DPP_R12 0x12C             // row_ror:12

template<int CTRL>
__device__ __forceinline__ float dppf(float v) {
    return __int_as_float(__builtin_amdgcn_update_dpp(
        0, __float_as_int(v), CTRL, 0xF, 0xF, true));
}

#define PIN(v) asm volatile("" : "+v"(v))

// f(a) = 1 + negB * rcp(1 + 2^a); a pre-scaled.
// sigmoid: negB=-1, a=L2E*x ;  tanh: negB=-2, a=2*L2E*x
__device__ __forceinline__ float act_pre(float a, float negB) {
    return fmaf(negB, __builtin_amdgcn_rcpf(1.0f + __builtin_amdgcn_exp2f(a)), 1.0f);
}

extern "C" __global__ void __launch_bounds__(64)
__attribute__((amdgpu_waves_per_eu(2, 2)))
lstm16dpp(const float* __restrict__ x,
          const float* __restrict__ wih0, const float* __restrict__ whh0,
          const float* __restrict__ bih0, const float* __restrict__ bhh0,
          const float* __restrict__ wih1, const float* __restrict__ whh1,
          const float* __restrict__ bih1, const float* __restrict__ bhh1,
          const float* __restrict__ fc1w, const float* __restrict__ fc1b,
          const float* __restrict__ fc2w, const float* __restrict__ fc2b,
          float* __restrict__ out, int nbatch)
{
    const int L    = threadIdx.x;                // 0..63
    const int l    = L & 15;                     // lane in row
    const int half = l >> 3;                     // 0: [i,f]; 1: [g,o]
    const int k    = l & 7;                      // unit (6,7 pad)
    const bool qe  = ((l >> 2) & 1) == 0;        // quads 0,2 own units 0-3

    int seq = blockIdx.x * 4 + (L >> 4);
    if (seq >= nbatch) seq = nbatch - 1;         // 8192 % 4 == 0: all live

    const float km = (k < 6) ? 1.0f : 0.0f;
    const int   kk = (k < 6) ? k : 0;

    const int r1 = (half ? 12 : 0) + kk;         // gate1 row: i or g
    const int r2 = (half ? 18 : 6) + kk;         // gate2 row: f or o
    const float s1 = km * (half ? TL2E : L2E);   // gate1 act scale
    const float s2 = km * L2E;                   // gate2 always sigmoid
    const float negB1 = half ? -2.0f : -1.0f;

    // ---- per-lane weights (48 floats) + biases, activation scales folded
    float wi0a[6], wi0b[6], wh0a[6], wh0b[6];
    float wi1a[6], wi1b[6], wh1a[6], wh1b[6];
#pragma unroll
    for (int j = 0; j < 6; ++j) {
        wi0a[j] = wih0[r1 * 6 + j] * s1;  wi0b[j] = wih0[r2 * 6 + j] * s2;
        wh0a[j] = whh0[r1 * 6 + j] * s1;  wh0b[j] = whh0[r2 * 6 + j] * s2;
        wi1a[j] = wih1[r1 * 6 + j] * s1;  wi1b[j] = wih1[r2 * 6 + j] * s2;
        wh1a[j] = whh1[r1 * 6 + j] * s1;  wh1b[j] = whh1[r2 * 6 + j] * s2;
    }
    float b0a = (bih0[r1] + bhh0[r1]) * s1, b0b = (bih0[r2] + bhh0[r2]) * s2;
    float b1a = (bih1[r1] + bhh1[r1]) * s1, b1b = (bih1[r2] + bhh1[r2]) * s2;

    // ---- FC head: rows 2l, 2l+1 (all 32 rows over 16 lanes)
    float fwA[6], fwB[6];
#pragma unroll
    for (int j = 0; j < 6; ++j) {
        fwA[j] = fc1w[(2 * l    ) * 6 + j];
        fwB[j] = fc1w[(2 * l + 1) * 6 + j];
    }
    float fbA = fc1b[2 * l], fbB = fc1b[2 * l + 1];
    float f2A = fc2w[2 * l], f2B = fc2w[2 * l + 1];
    const float f2b = fc2b[0];

#pragma unroll
    for (int j = 0; j < 6; ++j) {
        PIN(wi0a[j]); PIN(wi0b[j]); PIN(wh0a[j]); PIN(wh0b[j]);
        PIN(wi1a[j]); PIN(wi1b[j]); PIN(wh1a[j]); PIN(wh1b[j]);
        PIN(fwA[j]);  PIN(fwB[j]);
    }
    PIN(b0a); PIN(b0b); PIN(b1a); PIN(b1b);
    PIN(fbA); PIN(fbB); PIN(f2A); PIN(f2B);

    // ---- state: unit-ordered h (6 scalars each), c per lane
    float h0u[6], h1u[6];
#pragma unroll
    for (int j = 0; j < 6; ++j) { h0u[j] = 0.0f; h1u[j] = 0.0f; }
    float c0 = 0.0f, c1 = 0.0f;

    const float* xp = x + (size_t)seq * 3072;
    float*       op = out + (size_t)seq * 512;

    // ---- 2-deep x prefetch (3 x v2f per step)
    v2f xqA[3], xqB[3];
    xqA[0] = *(const v2f*)(xp + 0); xqA[1] = *(const v2f*)(xp + 2); xqA[2] = *(const v2f*)(xp + 4);
    xqB[0] = *(const v2f*)(xp + 6); xqB[1] = *(const v2f*)(xp + 8); xqB[2] = *(const v2f*)(xp + 10);

    // unit-ordered gather: h[unit j] -> HU_[j] on every lane of the row
#define GATHER(HU_, HV_)                                    \
    {                                                       \
        float u_  = dppf<DPP_R12>(HV_);                     \
        float hl_ = qe ? (HV_) : u_;                        \
        float hh_ = qe ? u_ : (HV_);                        \
        HU_[0] = dppf<DPP_B0>(hl_);                         \
        HU_[1] = dppf<DPP_B1>(hl_);                         \
        HU_[2] = dppf<DPP_B2>(hl_);                         \
        HU_[3] = dppf<DPP_B3>(hl_);                         \
        HU_[4] = dppf<DPP_B0>(hh_);                         \
        HU_[5] = dppf<DPP_B1>(hh_);                         \
    }

#define STEP(XC_, TP_, YV_)                                                     \
    {                                                                           \
        /* prefetch x[TP_] into XC_ at the end; issue loads now */              \
        const float* xr_ = xp + (TP_) * 6;                                      \
        v2f nx0_ = *(const v2f*)(xr_ + 0);                                      \
        v2f nx1_ = *(const v2f*)(xr_ + 2);                                      \
        v2f nx2_ = *(const v2f*)(xr_ + 4);                                      \
        /* cell1 recurrent partial (h1 only): hoisted off critical path */      \
        float p1a_ = b1a, p1b_ = b1b, q1a_ = 0.0f, q1b_ = 0.0f;                 \
        p1a_ = fmaf(wh1a[0], h1u[0], p1a_); q1a_ = fmaf(wh1a[1], h1u[1], q1a_); \
        p1a_ = fmaf(wh1a[2], h1u[2], p1a_); q1a_ = fmaf(wh1a[3], h1u[3], q1a_); \
        p1a_ = fmaf(wh1a[4], h1u[4], p1a_); q1a_ = fmaf(wh1a[5], h1u[5], q1a_); \
        p1b_ = fmaf(wh1b[0], h1u[0], p1b_); q1b_ = fmaf(wh1b[1], h1u[1], q1b_); \
        p1b_ = fmaf(wh1b[2], h1u[2], p1b_); q1b_ = fmaf(wh1b[3], h1u[3], q1b_); \
        p1b_ = fmaf(wh1b[4], h1u[4], p1b_); q1b_ = fmaf(wh1b[5], h1u[5], q1b_); \
        /* cell 0 gates: x-part + h-part, dual accumulators */                  \
        float a0a_ = b0a, a0b_ = b0b, z0a_ = 0.0f, z0b_ = 0.0f;                 \
        a0a_ = fmaf(wi0a[0], XC_[0].x, a0a_); z0a_ = fmaf(wi0a[1], XC_[0].y, z0a_); \
        a0a_ = fmaf(wi0a[2], XC_[1].x, a0a_); z0a_ = fmaf(wi0a[3], XC_[1].y, z0a_); \
        a0a_ = fmaf(wi0a[4], XC_[2].x, a0a_); z0a_ = fmaf(wi0a[5], XC_[2].y, z0a_); \
        a0b_ = fmaf(wi0b[0], XC_[0].x, a0b_); z0b_ = fmaf(wi0b[1], XC_[0].y, z0b_); \
        a0b_ = fmaf(wi0b[2], XC_[1].x, a0b_); z0b_ = fmaf(wi0b[3], XC_[1].y, z0b_); \
        a0b_ = fmaf(wi0b[4], XC_[2].x, a0b_); z0b_ = fmaf(wi0b[5], XC_[2].y, z0b_); \
        a0a_ = fmaf(wh0a[0], h0u[0], a0a_); z0a_ = fmaf(wh0a[1], h0u[1], z0a_); \
        a0a_ = fmaf(wh0a[2], h0u[2], a0a_); z0a_ = fmaf(wh0a[3], h0u[3], z0a_); \
        a0a_ = fmaf(wh0a[4], h0u[4], a0a_); z0a_ = fmaf(wh0a[5], h0u[5], z0a_); \
        a0b_ = fmaf(wh0b[0], h0u[0], a0b_); z0b_ = fmaf(wh0b[1], h0u[1], z0b_); \
        a0b_ = fmaf(wh0b[2], h0u[2], a0b_); z0b_ = fmaf(wh0b[3], h0u[3], z0b_); \
        a0b_ = fmaf(wh0b[4], h0u[4], a0b_); z0b_ = fmaf(wh0b[5], h0u[5], z0b_); \
        float A1_ = act_pre(a0a_ + z0a_, negB1);   /* i (half0) | g (half1) */  \
        float A2_ = act_pre(a0b_ + z0b_, -1.0f);   /* f (half0) | o (half1) */  \
        float S1_ = dppf<DPP_R8>(A1_);                                          \
        float S2_ = dppf<DPP_R8>(A2_);                                          \
        float fv_ = half ? S2_ : A2_;                                           \
        float ov_ = half ? A2_ : S2_;                                           \
        c0 = fmaf(fv_, c0, A1_ * S1_);             /* A1*S1 == i*g both halves */ \
        float h0_ = ov_ * act_pre(TL2E * c0, -2.0f);                            \
        GATHER(h0u, h0_);                                                       \
        /* cell 1 finish: input part over fresh h0 */                           \
        p1a_ = fmaf(wi1a[0], h0u[0], p1a_); q1a_ = fmaf(wi1a[1], h0u[1], q1a_); \
        p1a_ = fmaf(wi1a[2], h0u[2], p1a_); q1a_ = fmaf(wi1a[3], h0u[3], q1a_); \
        p1a_ = fmaf(wi1a[4], h0u[4], p1a_); q1a_ = fmaf(wi1a[5], h0u[5], q1a_); \
        p1b_ = fmaf(wi1b[0], h0u[0], p1b_); q1b_ = fmaf(wi1b[1], h0u[1], q1b_); \
        p1b_ = fmaf(wi1b[2], h0u[2], p1b_); q1b_ = fmaf(wi1b[3], h0u[3], q1b_); \
        p1b_ = fmaf(wi1b[4], h0u[4], p1b_); q1b_ = fmaf(wi1b[5], h0u[5], q1b_); \
        float B1_ = act_pre(p1a_ + q1a_, negB1);                                \
        float B2_ = act_pre(p1b_ + q1b_, -1.0f);                                \
        float T1_ = dppf<DPP_R8>(B1_);                                          \
        float T2_ = dppf<DPP_R8>(B2_);                                          \
        float fw_ = half ? T2_ : B2_;                                           \
        float ow_ = half ? B2_ : T2_;                                           \
        c1 = fmaf(fw_, c1, B1_ * T1_);                                          \
        float h1_ = ow_ * act_pre(TL2E * c1, -2.0f);                            \
        GATHER(h1u, h1_);                                                       \
        /* FC head on fresh h1 (2 rows/lane), rotate-add reduce over 16 */      \
        float rA_ = fbA, rB_ = fbB;                                             \
        rA_ = fmaf(fwA[0], h1u[0], rA_); rB_ = fmaf(fwB[0], h1u[0], rB_);       \
        rA_ = fmaf(fwA[1], h1u[1], rA_); rB_ = fmaf(fwB[1], h1u[1], rB_);       \
        rA_ = fmaf(fwA[2], h1u[2], rA_); rB_ = fmaf(fwB[2], h1u[2], rB_);       \
        rA_ = fmaf(fwA[3], h1u[3], rA_); rB_ = fmaf(fwB[3], h1u[3], rB_);       \
        rA_ = fmaf(fwA[4], h1u[4], rA_); rB_ = fmaf(fwB[4], h1u[4], rB_);       \
        rA_ = fmaf(fwA[5], h1u[5], rA_); rB_ = fmaf(fwB[5], h1u[5], rB_);       \
        float acc_ = fmaxf(rA_, 0.0f) * f2A;                                    \
        acc_ = fmaf(fmaxf(rB_, 0.0f), f2B, acc_);                               \
        acc_ += dppf<DPP_R1>(acc_);                                             \
        acc_ += dppf<DPP_R2>(acc_);                                             \
        acc_ += dppf<DPP_R4>(acc_);                                             \
        acc_ += dppf<DPP_R8>(acc_);                                             \
        YV_ = fmaxf(acc_ + f2b, 0.0f);                                          \
        /* rotate prefetched x into place */                                    \
        XC_[0] = nx0_; XC_[1] = nx1_; XC_[2] = nx2_;                            \
    }

    for (int t = 0; t < 512; t += 2) {
        float y0_, y1_;
        STEP(xqA, (t + 2 < 512 ? t + 2 : 510), y0_);
        STEP(xqB, (t + 3 < 512 ? t + 3 : 511), y1_);
        if ((L & 15) == 0) *(float2*)(op + t) = make_float2(y0_, y1_);
    }
#undef STEP
#undef GATHER
}

extern "C" void kernel_launch(void* const* d_in, const int* in_sizes, int n_in,
                              void* d_out, int out_size, void* d_ws, size_t ws_size,
                              hipStream_t stream) {
    const float* x     = (const float*)d_in[0];
    const float* wih0  = (const float*)d_in[1];
    const float* whh0  = (const float*)d_in[2];
    const float* bih0  = (const float*)d_in[3];
    const float* bhh0  = (const float*)d_in[4];
    const float* wih1  = (const float*)d_in[5];
    const float* whh1  = (const float*)d_in[6];
    const float* bih1  = (const float*)d_in[7];
    const float* bhh1  = (const float*)d_in[8];
    const float* fc1w  = (const float*)d_in[9];
    const float* fc1b  = (const float*)d_in[10];
    const float* fc2w  = (const float*)d_in[11];
    const float* fc2b  = (const float*)d_in[12];
    float* out = (float*)d_out;

    const int nbatch = in_sizes[0] / (512 * 6);     // 8192
    const int grid   = (nbatch + 3) / 4;            // 4 seqs per 64-thread wave

    hipLaunchKernelGGL(lstm16dpp, dim3(grid), dim3(64), 0, stream,
                       x, wih0, whh0, bih0, bhh0, wih1, whh1, bih1, bhh1,
                       fc1w, fc1b, fc2w, fc2b, out, nbatch);
}

// Round 8
// 242.598 us; speedup vs baseline: 1.0694x; 1.0694x over previous
//
#include <hip/hip_runtime.h>

// RIIDModelLSTM: 2-layer LSTM (H=6), T=512, B=8192, fused FC(6->32->1) head.
//
// v8 = v6 (zero-DS, DPP-only, 8 lanes/seq, pk-asm math; 199us) + stall cuts.
// Calibrated issue model from R5-R7: fma=2cyc, pk_fma=4cyc (no throughput
// gain, register-packing only), trans(exp/rcp)=16cyc issue-blocking, dpp=2.
// v6 busy (727cyc/step) == its issue floor; remaining 342cyc/step is
// dependency stall on gates->exp->rcp->c->tanh->h->gather->cell1.
//  1. X-PART HOIST: cell0's x-contribution for step t+1 (12 pk, depends only
//     on prefetched x) computed inside step t's activation-latency window.
//  2. NEWTON-RCP: the 10 v_rcp (trans, ~35cyc latency, on the c-chain) become
//     quad-seed + 2 Newton iters on y = 1+2^(-|a|) in (1,2] (full-rate fma,
//     ~24cyc latency, exact to ~1e-7). sigma(a-form) = (a<=0)? r : e*r.
// Mapping unchanged: seq = 8-lane coset {quad, quad+8} of a 16-lane row;
// p = (l&3)|((l>>3)<<2); lane p owns unit p (p=6,7 pad). 1024 waves, 1/SIMD.

typedef float v2f __attribute__((ext_vector_type(2)));

static constexpr float L2E  = 1.44269504088896340736f;
static constexpr float TL2E = 2.0f * L2E;

#define DPP_QP(a,b,c,d) ((a)|((b)<<2)|((c)<<4)|((d)<<6))
#define DPP_X1  DPP_QP(1,0,3,2)   // quad_perm xor-1
#define DPP_X2  DPP_QP(2,3,0,1)   // quad_perm xor-2
#define DPP_B0  DPP_QP(0,0,0,0)   // quad bcast lane0
#define DPP_B1  DPP_QP(1,1,1,1)
#define DPP_B2  DPP_QP(2,2,2,2)
#define DPP_B3  DPP_QP(3,3,3,3)
#define DPP_X8  0x128             // row_ror:8 = lane xor 8 inside 16-row

template<int CTRL>
__device__ __forceinline__ float dppf(float v) {
    return __int_as_float(__builtin_amdgcn_update_dpp(
        0, __float_as_int(v), CTRL, 0xF, 0xF, true));
}

#define PIN(v) asm volatile("" : "+v"(v))

// d += a * (b.lo, b.lo)   [VOP3P op_sel: src1 lo for both halves]
#define PKFMA_LO(d,a,b) asm("v_pk_fma_f32 %0, %1, %2, %0 op_sel:[0,0,0] op_sel_hi:[1,0,1]" : "+v"(d) : "v"(a), "v"(b))
// d += a * (b.hi, b.hi)
#define PKFMA_HI(d,a,b) asm("v_pk_fma_f32 %0, %1, %2, %0 op_sel:[0,1,0] op_sel_hi:[1,1,1]" : "+v"(d) : "v"(a), "v"(b))
#define PKADD(d,a,b)    asm("v_pk_add_f32 %0, %1, %2" : "=v"(d) : "v"(a), "v"(b))

// r ~= 1/(1+e), e in (0,1] -> y in (1,2]. Quad seed (~1.1% rel) + 2 Newton
// (err ~1e-8). Full-rate fma/mul only; replaces v_rcp (trans).
__device__ __forceinline__ float rcp1p(float e) {
    float y = 1.0f + e;
    float r = fmaf(y, fmaf(y, 0.32559f, -1.46518f), 2.13186f);
    r = r * fmaf(-y, r, 2.0f);
    r = r * fmaf(-y, r, 2.0f);
    return r;
}
// s = 1/(1+2^a) for any a: e = 2^(-|a|), r = 1/(1+e); a<=0 -> r, else e*r.
__device__ __forceinline__ float sig2(float a) {
    float e = __builtin_amdgcn_exp2f(-fabsf(a));
    float r = rcp1p(e);
    float m = (a <= 0.0f) ? 1.0f : e;
    return r * m;
}
// sigmoid with -L2E pre-folded into weights:  a = -L2E*x -> sigma(x)
__device__ __forceinline__ float sig_pre(float a) { return sig2(a); }
// tanh with +2*L2E pre-folded:  a = 2*L2E*x -> tanh(x) = 1 - 2/(1+2^a)
__device__ __forceinline__ float tanh_pre(float a) {
    return fmaf(-2.0f, sig2(a), 1.0f);
}

extern "C" __global__ void __launch_bounds__(64)
__attribute__((amdgpu_waves_per_eu(1, 1)))
lstm_dpp8v8(const float* __restrict__ x,
            const float* __restrict__ wih0, const float* __restrict__ whh0,
            const float* __restrict__ bih0, const float* __restrict__ bhh0,
            const float* __restrict__ wih1, const float* __restrict__ whh1,
            const float* __restrict__ bih1, const float* __restrict__ bhh1,
            const float* __restrict__ fc1w, const float* __restrict__ fc1b,
            const float* __restrict__ fc2w, const float* __restrict__ fc2b,
            float* __restrict__ out, int nbatch)
{
    const int L   = threadIdx.x;                 // 0..63
    const int l   = L & 15;
    const int row = L >> 4;                      // 0..3
    const int cst = (l >> 2) & 1;                // coset within row
    const int p   = (l & 3) | ((l >> 3) << 2);   // position in coset, 0..7
    const bool lowq = ((L >> 3) & 1) == 0;       // lane in units-0..3 quad

    int seq = blockIdx.x * 8 + row * 2 + cst;
    const bool live = (seq < nbatch);
    if (!live) seq = nbatch - 1;

    const float km = (p < 6) ? 1.0f : 0.0f;      // pad lanes 6,7
    const int   k  = (p < 6) ? p : 0;
    const int ir = k, fr = 6 + k, gr = 12 + k, orr = 18 + k;  // i,f,g,o rows

    // ---- weights. Gate pairs A=[i,f] (sigmoid,-L2E | sigmoid,-L2E),
    //               B=[g,o] (tanh,+2L2E | sigmoid,-L2E). Unit-ordered slots.
    v2f wiA0[6], wiB0[6];
    v2f whA0[6], whB0[6], wiA1[6], wiB1[6], whA1[6], whB1[6], f1wA[6], f1wB[6];
#pragma unroll
    for (int j = 0; j < 6; ++j) {
        wiA0[j] = (v2f){ wih0[ir*6+j]*(-L2E)*km,  wih0[fr*6+j]*(-L2E)*km };
        wiB0[j] = (v2f){ wih0[gr*6+j]*( TL2E)*km, wih0[orr*6+j]*(-L2E)*km };
        whA0[j] = (v2f){ whh0[ir*6+j]*(-L2E)*km,  whh0[fr*6+j]*(-L2E)*km };
        whB0[j] = (v2f){ whh0[gr*6+j]*( TL2E)*km, whh0[orr*6+j]*(-L2E)*km };
        wiA1[j] = (v2f){ wih1[ir*6+j]*(-L2E)*km,  wih1[fr*6+j]*(-L2E)*km };
        wiB1[j] = (v2f){ wih1[gr*6+j]*( TL2E)*km, wih1[orr*6+j]*(-L2E)*km };
        whA1[j] = (v2f){ whh1[ir*6+j]*(-L2E)*km,  whh1[fr*6+j]*(-L2E)*km };
        whB1[j] = (v2f){ whh1[gr*6+j]*( TL2E)*km, whh1[orr*6+j]*(-L2E)*km };
        f1wA[j] = (v2f){ fc1w[(4*p+0)*6+j], fc1w[(4*p+1)*6+j] };
        f1wB[j] = (v2f){ fc1w[(4*p+2)*6+j], fc1w[(4*p+3)*6+j] };
    }
    v2f bbA0 = (v2f){ (bih0[ir]+bhh0[ir])*(-L2E)*km,  (bih0[fr]+bhh0[fr])*(-L2E)*km };
    v2f bbB0 = (v2f){ (bih0[gr]+bhh0[gr])*( TL2E)*km, (bih0[orr]+bhh0[orr])*(-L2E)*km };
    v2f bbA1 = (v2f){ (bih1[ir]+bhh1[ir])*(-L2E)*km,  (bih1[fr]+bhh1[fr])*(-L2E)*km };
    v2f bbB1 = (v2f){ (bih1[gr]+bhh1[gr])*( TL2E)*km, (bih1[orr]+bhh1[orr])*(-L2E)*km };
    v2f f1bA = (v2f){ fc1b[4*p+0], fc1b[4*p+1] };
    v2f f1bB = (v2f){ fc1b[4*p+2], fc1b[4*p+3] };
    v2f f2wA = (v2f){ fc2w[4*p+0], fc2w[4*p+1] };
    v2f f2wB = (v2f){ fc2w[4*p+2], fc2w[4*p+3] };
    float f2b = fc2b[0];

#pragma unroll
    for (int j = 0; j < 6; ++j) {
        PIN(wiA0[j]); PIN(wiB0[j]); PIN(whA0[j]); PIN(whB0[j]);
        PIN(wiA1[j]); PIN(wiB1[j]); PIN(whA1[j]); PIN(whB1[j]);
        PIN(f1wA[j]); PIN(f1wB[j]);
    }
    PIN(bbA0); PIN(bbB0); PIN(bbA1); PIN(bbB1);
    PIN(f1bA); PIN(f1bB); PIN(f2wA); PIN(f2wB); PIN(f2b);

    // ---- state: h packed pairwise, units (0,1),(2,3),(4,5)
    v2f h0p[3], h1p[3];
    const v2f Z2 = (v2f){0.0f, 0.0f};
#pragma unroll
    for (int q = 0; q < 3; ++q) { h0p[q] = Z2; h1p[q] = Z2; }
    float c0 = 0.0f, c1 = 0.0f;

    const float* xp = x + (size_t)seq * (512 * 6);
    float*       op = out + (size_t)seq * 512;

    // ---- 4-deep x prefetch, pairs (x0,x1),(x2,x3),(x4,x5) as v2f
    v2f xq[4][3];
#pragma unroll
    for (int j = 0; j < 4; ++j) {
        const float* q = xp + j * 6;
        xq[j][0] = *(const v2f*)(q + 0);
        xq[j][1] = *(const v2f*)(q + 2);
        xq[j][2] = *(const v2f*)(q + 4);
    }

    // unit-ordered gather: h[unit j] -> slot j on every lane, 6 slots
#define GATHER(HP_, HV_)                                                        \
    {                                                                           \
        float u_ = dppf<DPP_X8>(HV_);            /* partner quad's h */         \
        float hl = lowq ? (HV_) : u_;            /* units 0-3 @ quad pos */     \
        float hh = lowq ? u_ : (HV_);            /* units 4-7 @ quad pos */     \
        HP_[0] = (v2f){ dppf<DPP_B0>(hl), dppf<DPP_B1>(hl) };                   \
        HP_[1] = (v2f){ dppf<DPP_B2>(hl), dppf<DPP_B3>(hl) };                   \
        HP_[2] = (v2f){ dppf<DPP_B0>(hh), dppf<DPP_B1>(hh) };                   \
    }

    // ---- cell0 x-part accumulators for the CURRENT step (hoisted by 1 step)
    v2f xgA, xgA2, xgB, xgB2;
    {
        xgA = bbA0; xgA2 = Z2; xgB = bbB0; xgB2 = Z2;
        PKFMA_LO(xgA, wiA0[0], xq[0][0]); PKFMA_HI(xgA2, wiA0[1], xq[0][0]);
        PKFMA_LO(xgA, wiA0[2], xq[0][1]); PKFMA_HI(xgA2, wiA0[3], xq[0][1]);
        PKFMA_LO(xgA, wiA0[4], xq[0][2]); PKFMA_HI(xgA2, wiA0[5], xq[0][2]);
        PKFMA_LO(xgB, wiB0[0], xq[0][0]); PKFMA_HI(xgB2, wiB0[1], xq[0][0]);
        PKFMA_LO(xgB, wiB0[2], xq[0][1]); PKFMA_HI(xgB2, wiB0[3], xq[0][1]);
        PKFMA_LO(xgB, wiB0[4], xq[0][2]); PKFMA_HI(xgB2, wiB0[5], xq[0][2]);
    }

    float y[4];

    for (int T = 0; T < 512; T += 4) {
        const int Tn = (T < 508) ? T + 4 : 508;   // clamped prefetch base
#pragma unroll
        for (int j = 0; j < 4; ++j) {
            // -- issue x[T+j+4] loads early (consumed next outer iter)
            const float* xr = xp + (Tn + j) * 6;
            v2f nx0 = *(const v2f*)(xr + 0);
            v2f nx1 = *(const v2f*)(xr + 2);
            v2f nx2 = *(const v2f*)(xr + 4);

            // -- cell1 recurrent partial (depends only on h1p): hoisted
            v2f pA = bbA1, pA2 = Z2, pB = bbB1, pB2 = Z2;
            PKFMA_LO(pA, whA1[0], h1p[0]); PKFMA_HI(pA2, whA1[1], h1p[0]);
            PKFMA_LO(pA, whA1[2], h1p[1]); PKFMA_HI(pA2, whA1[3], h1p[1]);
            PKFMA_LO(pA, whA1[4], h1p[2]); PKFMA_HI(pA2, whA1[5], h1p[2]);
            PKFMA_LO(pB, whB1[0], h1p[0]); PKFMA_HI(pB2, whB1[1], h1p[0]);
            PKFMA_LO(pB, whB1[2], h1p[1]); PKFMA_HI(pB2, whB1[3], h1p[1]);
            PKFMA_LO(pB, whB1[4], h1p[2]); PKFMA_HI(pB2, whB1[5], h1p[2]);

            // -- cell 0 gates: start from precomputed x-part, add h-part
            v2f aA = xgA, aA2 = xgA2, aB = xgB, aB2 = xgB2;
            PKFMA_LO(aA, whA0[0], h0p[0]);  PKFMA_HI(aA2, whA0[1], h0p[0]);
            PKFMA_LO(aA, whA0[2], h0p[1]);  PKFMA_HI(aA2, whA0[3], h0p[1]);
            PKFMA_LO(aA, whA0[4], h0p[2]);  PKFMA_HI(aA2, whA0[5], h0p[2]);
            PKFMA_LO(aB, whB0[0], h0p[0]);  PKFMA_HI(aB2, whB0[1], h0p[0]);
            PKFMA_LO(aB, whB0[2], h0p[1]);  PKFMA_HI(aB2, whB0[3], h0p[1]);
            PKFMA_LO(aB, whB0[4], h0p[2]);  PKFMA_HI(aB2, whB0[5], h0p[2]);
            v2f gA0, gB0;
            PKADD(gA0, aA, aA2);
            PKADD(gB0, aB, aB2);

            float i0 = sig_pre(gA0.x), f0 = sig_pre(gA0.y);
            float g0 = tanh_pre(gB0.x), o0 = sig_pre(gB0.y);

            // -- x-part for step t+1 (only needs prefetched x): latency filler
            //    for the activation chain above.
            {
                const v2f* xn = xq[(j + 1) & 3];
                v2f tA = bbA0, tA2 = Z2, tB = bbB0, tB2 = Z2;
                PKFMA_LO(tA, wiA0[0], xn[0]); PKFMA_HI(tA2, wiA0[1], xn[0]);
                PKFMA_LO(tA, wiA0[2], xn[1]); PKFMA_HI(tA2, wiA0[3], xn[1]);
                PKFMA_LO(tA, wiA0[4], xn[2]); PKFMA_HI(tA2, wiA0[5], xn[2]);
                PKFMA_LO(tB, wiB0[0], xn[0]); PKFMA_HI(tB2, wiB0[1], xn[0]);
                PKFMA_LO(tB, wiB0[2], xn[1]); PKFMA_HI(tB2, wiB0[3], xn[1]);
                PKFMA_LO(tB, wiB0[4], xn[2]); PKFMA_HI(tB2, wiB0[5], xn[2]);
                xgA = tA; xgA2 = tA2; xgB = tB; xgB2 = tB2;
            }

            c0 = fmaf(f0, c0, i0 * g0);
            float h0 = o0 * tanh_pre(TL2E * c0);

            GATHER(h0p, h0);

            // -- cell 1 finish (input part over fresh h0)
            PKFMA_LO(pA, wiA1[0], h0p[0]); PKFMA_HI(pA2, wiA1[1], h0p[0]);
            PKFMA_LO(pA, wiA1[2], h0p[1]); PKFMA_HI(pA2, wiA1[3], h0p[1]);
            PKFMA_LO(pA, wiA1[4], h0p[2]); PKFMA_HI(pA2, wiA1[5], h0p[2]);
            PKFMA_LO(pB, wiB1[0], h0p[0]); PKFMA_HI(pB2, wiB1[1], h0p[0]);
            PKFMA_LO(pB, wiB1[2], h0p[1]); PKFMA_HI(pB2, wiB1[3], h0p[1]);
            PKFMA_LO(pB, wiB1[4], h0p[2]); PKFMA_HI(pB2, wiB1[5], h0p[2]);
            v2f gA1, gB1;
            PKADD(gA1, pA, pA2);
            PKADD(gB1, pB, pB2);

            float i1 = sig_pre(gA1.x), f1 = sig_pre(gA1.y);
            float g1 = tanh_pre(gB1.x), o1 = sig_pre(gB1.y);
            c1 = fmaf(f1, c1, i1 * g1);
            float h1 = o1 * tanh_pre(TL2E * c1);

            GATHER(h1p, h1);

            // -- FC head on fresh h1 (independent of next step's recurrence)
            v2f rA = f1bA, rA2 = Z2, rB = f1bB, rB2 = Z2;
            PKFMA_LO(rA, f1wA[0], h1p[0]); PKFMA_HI(rA2, f1wA[1], h1p[0]);
            PKFMA_LO(rA, f1wA[2], h1p[1]); PKFMA_HI(rA2, f1wA[3], h1p[1]);
            PKFMA_LO(rA, f1wA[4], h1p[2]); PKFMA_HI(rA2, f1wA[5], h1p[2]);
            PKFMA_LO(rB, f1wB[0], h1p[0]); PKFMA_HI(rB2, f1wB[1], h1p[0]);
            PKFMA_LO(rB, f1wB[2], h1p[1]); PKFMA_HI(rB2, f1wB[3], h1p[1]);
            PKFMA_LO(rB, f1wB[4], h1p[2]); PKFMA_HI(rB2, f1wB[5], h1p[2]);
            v2f RA, RB;
            PKADD(RA, rA, rA2);
            PKADD(RB, rB, rB2);
            float acc =          fmaxf(RA.x, 0.0f) * f2wA.x;
            acc = fmaf(fmaxf(RA.y, 0.0f), f2wA.y, acc);
            acc = fmaf(fmaxf(RB.x, 0.0f), f2wB.x, acc);
            acc = fmaf(fmaxf(RB.y, 0.0f), f2wB.y, acc);
            // butterfly reduce over the 8-lane coset (pure VALU)
            acc += dppf<DPP_X1>(acc);
            acc += dppf<DPP_X2>(acc);
            acc += dppf<DPP_X8>(acc);
            y[j] = fmaxf(acc + f2b, 0.0f);

            // -- rotate x prefetch
            xq[j][0] = nx0; xq[j][1] = nx1; xq[j][2] = nx2;
        }
        // -- one coalesced 16B out-store per 4 steps (lane p==0 of each coset)
        if (live && ((L & 11) == 0)) {
            float4 yv = make_float4(y[0], y[1], y[2], y[3]);
            *(float4*)(op + T) = yv;
        }
    }
}

extern "C" void kernel_launch(void* const* d_in, const int* in_sizes, int n_in,
                              void* d_out, int out_size, void* d_ws, size_t ws_size,
                              hipStream_t stream) {
    const float* x     = (const float*)d_in[0];
    const float* wih0  = (const float*)d_in[1];
    const float* whh0  = (const float*)d_in[2];
    const float* bih0  = (const float*)d_in[3];
    const float* bhh0  = (const float*)d_in[4];
    const float* wih1  = (const float*)d_in[5];
    const float* whh1  = (const float*)d_in[6];
    const float* bih1  = (const float*)d_in[7];
    const float* bhh1  = (const float*)d_in[8];
    const float* fc1w  = (const float*)d_in[9];
    const float* fc1b  = (const float*)d_in[10];
    const float* fc2w  = (const float*)d_in[11];
    const float* fc2b  = (const float*)d_in[12];
    float* out = (float*)d_out;

    const int nbatch = in_sizes[0] / (512 * 6);     // 8192
    const int grid   = (nbatch + 7) / 8;            // 8 seqs per 64-thread wave

    hipLaunchKernelGGL(lstm_dpp8v8, dim3(grid), dim3(64), 0, stream,
                       x, wih0, whh0, bih0, bhh0, wih1, whh1, bih1, bhh1,
                       fc1w, fc1b, fc2w, fc2b, out, nbatch);
}

// Round 9
// 182.598 us; speedup vs baseline: 1.4208x; 1.3286x over previous
//
#include <hip/hip_runtime.h>

// RIIDModelLSTM: 2-layer LSTM (H=6), T=512, B=8192, fused FC(6->32->1) head.
//
// v9 = v6 (zero-DS, DPP-only, 8 lanes/seq, pk-asm math; 199us)
//      + v8's X-PART HOIST (stall filler: confirmed, stall 300->~200 cyc/step)
//      - v8's Newton-rcp (REVERTED: traded 10 quarter-rate v_rcp (~8cyc issue)
//        for ~20 full-rate VALU ops each => +300 busy cyc/step. Trans issue
//        is ~8cyc, not 16 -- replacing trans with FMA chains loses.)
// Activations back to v6's exact arithmetic: f(a) with exp2+v_rcp, scales
// pre-folded into weights.
// Mapping: seq = 8-lane coset {quad, quad+8} of a 16-lane row;
// p = (l&3)|((l>>3)<<2); lane p owns unit p (p=6,7 pad). 1024 waves, 1/SIMD.

typedef float v2f __attribute__((ext_vector_type(2)));

static constexpr float L2E  = 1.44269504088896340736f;
static constexpr float TL2E = 2.0f * L2E;

#define DPP_QP(a,b,c,d) ((a)|((b)<<2)|((c)<<4)|((d)<<6))
#define DPP_X1  DPP_QP(1,0,3,2)   // quad_perm xor-1
#define DPP_X2  DPP_QP(2,3,0,1)   // quad_perm xor-2
#define DPP_B0  DPP_QP(0,0,0,0)   // quad bcast lane0
#define DPP_B1  DPP_QP(1,1,1,1)
#define DPP_B2  DPP_QP(2,2,2,2)
#define DPP_B3  DPP_QP(3,3,3,3)
#define DPP_X8  0x128             // row_ror:8 = lane xor 8 inside 16-row

template<int CTRL>
__device__ __forceinline__ float dppf(float v) {
    return __int_as_float(__builtin_amdgcn_update_dpp(
        0, __float_as_int(v), CTRL, 0xF, 0xF, true));
}

#define PIN(v) asm volatile("" : "+v"(v))

// d += a * (b.lo, b.lo)   [VOP3P op_sel: src1 lo for both halves]
#define PKFMA_LO(d,a,b) asm("v_pk_fma_f32 %0, %1, %2, %0 op_sel:[0,0,0] op_sel_hi:[1,0,1]" : "+v"(d) : "v"(a), "v"(b))
// d += a * (b.hi, b.hi)
#define PKFMA_HI(d,a,b) asm("v_pk_fma_f32 %0, %1, %2, %0 op_sel:[0,1,0] op_sel_hi:[1,1,1]" : "+v"(d) : "v"(a), "v"(b))
#define PKADD(d,a,b)    asm("v_pk_add_f32 %0, %1, %2" : "=v"(d) : "v"(a), "v"(b))

// sigmoid with -L2E pre-folded into weights:  a = -L2E*x -> 1/(1+2^a)
__device__ __forceinline__ float sig_pre(float a) {
    return __builtin_amdgcn_rcpf(1.0f + __builtin_amdgcn_exp2f(a));
}
// tanh with +2*L2E pre-folded:  a = 2*L2E*x -> tanh(x) = 1 - 2/(1+2^a)
__device__ __forceinline__ float tanh_pre(float a) {
    return fmaf(-2.0f, __builtin_amdgcn_rcpf(1.0f + __builtin_amdgcn_exp2f(a)), 1.0f);
}

extern "C" __global__ void __launch_bounds__(64)
__attribute__((amdgpu_waves_per_eu(1, 1)))
lstm_dpp8v9(const float* __restrict__ x,
            const float* __restrict__ wih0, const float* __restrict__ whh0,
            const float* __restrict__ bih0, const float* __restrict__ bhh0,
            const float* __restrict__ wih1, const float* __restrict__ whh1,
            const float* __restrict__ bih1, const float* __restrict__ bhh1,
            const float* __restrict__ fc1w, const float* __restrict__ fc1b,
            const float* __restrict__ fc2w, const float* __restrict__ fc2b,
            float* __restrict__ out, int nbatch)
{
    const int L   = threadIdx.x;                 // 0..63
    const int l   = L & 15;
    const int row = L >> 4;                      // 0..3
    const int cst = (l >> 2) & 1;                // coset within row
    const int p   = (l & 3) | ((l >> 3) << 2);   // position in coset, 0..7
    const bool lowq = ((L >> 3) & 1) == 0;       // lane in units-0..3 quad

    int seq = blockIdx.x * 8 + row * 2 + cst;
    const bool live = (seq < nbatch);
    if (!live) seq = nbatch - 1;

    const float km = (p < 6) ? 1.0f : 0.0f;      // pad lanes 6,7
    const int   k  = (p < 6) ? p : 0;
    const int ir = k, fr = 6 + k, gr = 12 + k, orr = 18 + k;  // i,f,g,o rows

    // ---- weights. Gate pairs A=[i,f] (sigmoid,-L2E | sigmoid,-L2E),
    //               B=[g,o] (tanh,+2L2E | sigmoid,-L2E). Unit-ordered slots.
    v2f wiA0[6], wiB0[6];
    v2f whA0[6], whB0[6], wiA1[6], wiB1[6], whA1[6], whB1[6], f1wA[6], f1wB[6];
#pragma unroll
    for (int j = 0; j < 6; ++j) {
        wiA0[j] = (v2f){ wih0[ir*6+j]*(-L2E)*km,  wih0[fr*6+j]*(-L2E)*km };
        wiB0[j] = (v2f){ wih0[gr*6+j]*( TL2E)*km, wih0[orr*6+j]*(-L2E)*km };
        whA0[j] = (v2f){ whh0[ir*6+j]*(-L2E)*km,  whh0[fr*6+j]*(-L2E)*km };
        whB0[j] = (v2f){ whh0[gr*6+j]*( TL2E)*km, whh0[orr*6+j]*(-L2E)*km };
        wiA1[j] = (v2f){ wih1[ir*6+j]*(-L2E)*km,  wih1[fr*6+j]*(-L2E)*km };
        wiB1[j] = (v2f){ wih1[gr*6+j]*( TL2E)*km, wih1[orr*6+j]*(-L2E)*km };
        whA1[j] = (v2f){ whh1[ir*6+j]*(-L2E)*km,  whh1[fr*6+j]*(-L2E)*km };
        whB1[j] = (v2f){ whh1[gr*6+j]*( TL2E)*km, whh1[orr*6+j]*(-L2E)*km };
        f1wA[j] = (v2f){ fc1w[(4*p+0)*6+j], fc1w[(4*p+1)*6+j] };
        f1wB[j] = (v2f){ fc1w[(4*p+2)*6+j], fc1w[(4*p+3)*6+j] };
    }
    v2f bbA0 = (v2f){ (bih0[ir]+bhh0[ir])*(-L2E)*km,  (bih0[fr]+bhh0[fr])*(-L2E)*km };
    v2f bbB0 = (v2f){ (bih0[gr]+bhh0[gr])*( TL2E)*km, (bih0[orr]+bhh0[orr])*(-L2E)*km };
    v2f bbA1 = (v2f){ (bih1[ir]+bhh1[ir])*(-L2E)*km,  (bih1[fr]+bhh1[fr])*(-L2E)*km };
    v2f bbB1 = (v2f){ (bih1[gr]+bhh1[gr])*( TL2E)*km, (bih1[orr]+bhh1[orr])*(-L2E)*km };
    v2f f1bA = (v2f){ fc1b[4*p+0], fc1b[4*p+1] };
    v2f f1bB = (v2f){ fc1b[4*p+2], fc1b[4*p+3] };
    v2f f2wA = (v2f){ fc2w[4*p+0], fc2w[4*p+1] };
    v2f f2wB = (v2f){ fc2w[4*p+2], fc2w[4*p+3] };
    float f2b = fc2b[0];

#pragma unroll
    for (int j = 0; j < 6; ++j) {
        PIN(wiA0[j]); PIN(wiB0[j]); PIN(whA0[j]); PIN(whB0[j]);
        PIN(wiA1[j]); PIN(wiB1[j]); PIN(whA1[j]); PIN(whB1[j]);
        PIN(f1wA[j]); PIN(f1wB[j]);
    }
    PIN(bbA0); PIN(bbB0); PIN(bbA1); PIN(bbB1);
    PIN(f1bA); PIN(f1bB); PIN(f2wA); PIN(f2wB); PIN(f2b);

    // ---- state: h packed pairwise, units (0,1),(2,3),(4,5)
    v2f h0p[3], h1p[3];
    const v2f Z2 = (v2f){0.0f, 0.0f};
#pragma unroll
    for (int q = 0; q < 3; ++q) { h0p[q] = Z2; h1p[q] = Z2; }
    float c0 = 0.0f, c1 = 0.0f;

    const float* xp = x + (size_t)seq * (512 * 6);
    float*       op = out + (size_t)seq * 512;

    // ---- 4-deep x prefetch, pairs (x0,x1),(x2,x3),(x4,x5) as v2f
    v2f xq[4][3];
#pragma unroll
    for (int j = 0; j < 4; ++j) {
        const float* q = xp + j * 6;
        xq[j][0] = *(const v2f*)(q + 0);
        xq[j][1] = *(const v2f*)(q + 2);
        xq[j][2] = *(const v2f*)(q + 4);
    }

    // unit-ordered gather: h[unit j] -> slot j on every lane, 6 slots
#define GATHER(HP_, HV_)                                                        \
    {                                                                           \
        float u_ = dppf<DPP_X8>(HV_);            /* partner quad's h */         \
        float hl = lowq ? (HV_) : u_;            /* units 0-3 @ quad pos */     \
        float hh = lowq ? u_ : (HV_);            /* units 4-7 @ quad pos */     \
        HP_[0] = (v2f){ dppf<DPP_B0>(hl), dppf<DPP_B1>(hl) };                   \
        HP_[1] = (v2f){ dppf<DPP_B2>(hl), dppf<DPP_B3>(hl) };                   \
        HP_[2] = (v2f){ dppf<DPP_B0>(hh), dppf<DPP_B1>(hh) };                   \
    }

    // ---- cell0 x-part accumulators for the CURRENT step (hoisted by 1 step)
    v2f xgA, xgA2, xgB, xgB2;
    {
        xgA = bbA0; xgA2 = Z2; xgB = bbB0; xgB2 = Z2;
        PKFMA_LO(xgA, wiA0[0], xq[0][0]); PKFMA_HI(xgA2, wiA0[1], xq[0][0]);
        PKFMA_LO(xgA, wiA0[2], xq[0][1]); PKFMA_HI(xgA2, wiA0[3], xq[0][1]);
        PKFMA_LO(xgA, wiA0[4], xq[0][2]); PKFMA_HI(xgA2, wiA0[5], xq[0][2]);
        PKFMA_LO(xgB, wiB0[0], xq[0][0]); PKFMA_HI(xgB2, wiB0[1], xq[0][0]);
        PKFMA_LO(xgB, wiB0[2], xq[0][1]); PKFMA_HI(xgB2, wiB0[3], xq[0][1]);
        PKFMA_LO(xgB, wiB0[4], xq[0][2]); PKFMA_HI(xgB2, wiB0[5], xq[0][2]);
    }

    float y[4];

    for (int T = 0; T < 512; T += 4) {
        const int Tn = (T < 508) ? T + 4 : 508;   // clamped prefetch base
#pragma unroll
        for (int j = 0; j < 4; ++j) {
            // -- issue x[T+j+4] loads early (consumed next outer iter)
            const float* xr = xp + (Tn + j) * 6;
            v2f nx0 = *(const v2f*)(xr + 0);
            v2f nx1 = *(const v2f*)(xr + 2);
            v2f nx2 = *(const v2f*)(xr + 4);

            // -- cell1 recurrent partial (depends only on h1p): hoisted
            v2f pA = bbA1, pA2 = Z2, pB = bbB1, pB2 = Z2;
            PKFMA_LO(pA, whA1[0], h1p[0]); PKFMA_HI(pA2, whA1[1], h1p[0]);
            PKFMA_LO(pA, whA1[2], h1p[1]); PKFMA_HI(pA2, whA1[3], h1p[1]);
            PKFMA_LO(pA, whA1[4], h1p[2]); PKFMA_HI(pA2, whA1[5], h1p[2]);
            PKFMA_LO(pB, whB1[0], h1p[0]); PKFMA_HI(pB2, whB1[1], h1p[0]);
            PKFMA_LO(pB, whB1[2], h1p[1]); PKFMA_HI(pB2, whB1[3], h1p[1]);
            PKFMA_LO(pB, whB1[4], h1p[2]); PKFMA_HI(pB2, whB1[5], h1p[2]);

            // -- cell 0 gates: start from precomputed x-part, add h-part
            v2f aA = xgA, aA2 = xgA2, aB = xgB, aB2 = xgB2;
            PKFMA_LO(aA, whA0[0], h0p[0]);  PKFMA_HI(aA2, whA0[1], h0p[0]);
            PKFMA_LO(aA, whA0[2], h0p[1]);  PKFMA_HI(aA2, whA0[3], h0p[1]);
            PKFMA_LO(aA, whA0[4], h0p[2]);  PKFMA_HI(aA2, whA0[5], h0p[2]);
            PKFMA_LO(aB, whB0[0], h0p[0]);  PKFMA_HI(aB2, whB0[1], h0p[0]);
            PKFMA_LO(aB, whB0[2], h0p[1]);  PKFMA_HI(aB2, whB0[3], h0p[1]);
            PKFMA_LO(aB, whB0[4], h0p[2]);  PKFMA_HI(aB2, whB0[5], h0p[2]);
            v2f gA0, gB0;
            PKADD(gA0, aA, aA2);
            PKADD(gB0, aB, aB2);

            float i0 = sig_pre(gA0.x), f0 = sig_pre(gA0.y);
            float g0 = tanh_pre(gB0.x), o0 = sig_pre(gB0.y);

            // -- x-part for step t+1 (only needs prefetched x): latency filler
            //    for the activation chain above.
            {
                const v2f* xn = xq[(j + 1) & 3];
                v2f tA = bbA0, tA2 = Z2, tB = bbB0, tB2 = Z2;
                PKFMA_LO(tA, wiA0[0], xn[0]); PKFMA_HI(tA2, wiA0[1], xn[0]);
                PKFMA_LO(tA, wiA0[2], xn[1]); PKFMA_HI(tA2, wiA0[3], xn[1]);
                PKFMA_LO(tA, wiA0[4], xn[2]); PKFMA_HI(tA2, wiA0[5], xn[2]);
                PKFMA_LO(tB, wiB0[0], xn[0]); PKFMA_HI(tB2, wiB0[1], xn[0]);
                PKFMA_LO(tB, wiB0[2], xn[1]); PKFMA_HI(tB2, wiB0[3], xn[1]);
                PKFMA_LO(tB, wiB0[4], xn[2]); PKFMA_HI(tB2, wiB0[5], xn[2]);
                xgA = tA; xgA2 = tA2; xgB = tB; xgB2 = tB2;
            }

            c0 = fmaf(f0, c0, i0 * g0);
            float h0 = o0 * tanh_pre(TL2E * c0);

            GATHER(h0p, h0);

            // -- cell 1 finish (input part over fresh h0)
            PKFMA_LO(pA, wiA1[0], h0p[0]); PKFMA_HI(pA2, wiA1[1], h0p[0]);
            PKFMA_LO(pA, wiA1[2], h0p[1]); PKFMA_HI(pA2, wiA1[3], h0p[1]);
            PKFMA_LO(pA, wiA1[4], h0p[2]); PKFMA_HI(pA2, wiA1[5], h0p[2]);
            PKFMA_LO(pB, wiB1[0], h0p[0]); PKFMA_HI(pB2, wiB1[1], h0p[0]);
            PKFMA_LO(pB, wiB1[2], h0p[1]); PKFMA_HI(pB2, wiB1[3], h0p[1]);
            PKFMA_LO(pB, wiB1[4], h0p[2]); PKFMA_HI(pB2, wiB1[5], h0p[2]);
            v2f gA1, gB1;
            PKADD(gA1, pA, pA2);
            PKADD(gB1, pB, pB2);

            float i1 = sig_pre(gA1.x), f1 = sig_pre(gA1.y);
            float g1 = tanh_pre(gB1.x), o1 = sig_pre(gB1.y);
            c1 = fmaf(f1, c1, i1 * g1);
            float h1 = o1 * tanh_pre(TL2E * c1);

            GATHER(h1p, h1);

            // -- FC head on fresh h1 (independent of next step's recurrence)
            v2f rA = f1bA, rA2 = Z2, rB = f1bB, rB2 = Z2;
            PKFMA_LO(rA, f1wA[0], h1p[0]); PKFMA_HI(rA2, f1wA[1], h1p[0]);
            PKFMA_LO(rA, f1wA[2], h1p[1]); PKFMA_HI(rA2, f1wA[3], h1p[1]);
            PKFMA_LO(rA, f1wA[4], h1p[2]); PKFMA_HI(rA2, f1wA[5], h1p[2]);
            PKFMA_LO(rB, f1wB[0], h1p[0]); PKFMA_HI(rB2, f1wB[1], h1p[0]);
            PKFMA_LO(rB, f1wB[2], h1p[1]); PKFMA_HI(rB2, f1wB[3], h1p[1]);
            PKFMA_LO(rB, f1wB[4], h1p[2]); PKFMA_HI(rB2, f1wB[5], h1p[2]);
            v2f RA, RB;
            PKADD(RA, rA, rA2);
            PKADD(RB, rB, rB2);
            float acc =          fmaxf(RA.x, 0.0f) * f2wA.x;
            acc = fmaf(fmaxf(RA.y, 0.0f), f2wA.y, acc);
            acc = fmaf(fmaxf(RB.x, 0.0f), f2wB.x, acc);
            acc = fmaf(fmaxf(RB.y, 0.0f), f2wB.y, acc);
            // butterfly reduce over the 8-lane coset (pure VALU)
            acc += dppf<DPP_X1>(acc);
            acc += dppf<DPP_X2>(acc);
            acc += dppf<DPP_X8>(acc);
            y[j] = fmaxf(acc + f2b, 0.0f);

            // -- rotate x prefetch
            xq[j][0] = nx0; xq[j][1] = nx1; xq[j][2] = nx2;
        }
        // -- one coalesced 16B out-store per 4 steps (lane p==0 of each coset)
        if (live && ((L & 11) == 0)) {
            float4 yv = make_float4(y[0], y[1], y[2], y[3]);
            *(float4*)(op + T) = yv;
        }
    }
}

extern "C" void kernel_launch(void* const* d_in, const int* in_sizes, int n_in,
                              void* d_out, int out_size, void* d_ws, size_t ws_size,
                              hipStream_t stream) {
    const float* x     = (const float*)d_in[0];
    const float* wih0  = (const float*)d_in[1];
    const float* whh0  = (const float*)d_in[2];
    const float* bih0  = (const float*)d_in[3];
    const float* bhh0  = (const float*)d_in[4];
    const float* wih1  = (const float*)d_in[5];
    const float* whh1  = (const float*)d_in[6];
    const float* bih1  = (const float*)d_in[7];
    const float* bhh1  = (const float*)d_in[8];
    const float* fc1w  = (const float*)d_in[9];
    const float* fc1b  = (const float*)d_in[10];
    const float* fc2w  = (const float*)d_in[11];
    const float* fc2b  = (const float*)d_in[12];
    float* out = (float*)d_out;

    const int nbatch = in_sizes[0] / (512 * 6);     // 8192
    const int grid   = (nbatch + 7) / 8;            // 8 seqs per 64-thread wave

    hipLaunchKernelGGL(lstm_dpp8v9, dim3(grid), dim3(64), 0, stream,
                       x, wih0, whh0, bih0, bhh0, wih1, whh1, bih1, bhh1,
                       fc1w, fc1b, fc2w, fc2b, out, nbatch);
}

// Round 10
// 181.182 us; speedup vs baseline: 1.4320x; 1.0078x over previous
//
#include <hip/hip_runtime.h>

// RIIDModelLSTM: 2-layer LSTM (H=6), T=512, B=8192, fused FC(6->32->1) head.
//
// v10 = v9 (182.6us) + CRITICAL-PATH ROTATION of cell0's h-part.
// R9 accounting: 856 cyc/step = 646 busy (within ~10% of issue floor:
// 60 pk_fma*4 + trans + glue) + 210 stall. In v9, step t opened with 12
// pk_fma (whA0*h0p) ON the critical path before gates0 could close, while
// act1/tanh(c1)'s latency window had zero independent filler (x-part fills
// act0; FC needs h1). v10: accumulate whA0*h0p(t) into the NEXT step's gate
// accumulators DURING step t's act1 window. The xg* registers become full
// gate0 preactivations (bias -> x-FMAs in act0 window -> wh-FMAs in act1
// window; same per-accumulator order => bit-identical math). Step t+1 then
// opens with just 2 pk_add -> act0 starts ~48cyc earlier, act1 gains filler.
// Mapping unchanged: 8-lane coset/seq, p=(l&3)|((l>>3)<<2), zero-DS,
// DPP-only, 1024 waves = 1/SIMD.

typedef float v2f __attribute__((ext_vector_type(2)));

static constexpr float L2E  = 1.44269504088896340736f;
static constexpr float TL2E = 2.0f * L2E;

#define DPP_QP(a,b,c,d) ((a)|((b)<<2)|((c)<<4)|((d)<<6))
#define DPP_X1  DPP_QP(1,0,3,2)   // quad_perm xor-1
#define DPP_X2  DPP_QP(2,3,0,1)   // quad_perm xor-2
#define DPP_B0  DPP_QP(0,0,0,0)   // quad bcast lane0
#define DPP_B1  DPP_QP(1,1,1,1)
#define DPP_B2  DPP_QP(2,2,2,2)
#define DPP_B3  DPP_QP(3,3,3,3)
#define DPP_X8  0x128             // row_ror:8 = lane xor 8 inside 16-row

template<int CTRL>
__device__ __forceinline__ float dppf(float v) {
    return __int_as_float(__builtin_amdgcn_update_dpp(
        0, __float_as_int(v), CTRL, 0xF, 0xF, true));
}

#define PIN(v) asm volatile("" : "+v"(v))

// d += a * (b.lo, b.lo)   [VOP3P op_sel: src1 lo for both halves]
#define PKFMA_LO(d,a,b) asm("v_pk_fma_f32 %0, %1, %2, %0 op_sel:[0,0,0] op_sel_hi:[1,0,1]" : "+v"(d) : "v"(a), "v"(b))
// d += a * (b.hi, b.hi)
#define PKFMA_HI(d,a,b) asm("v_pk_fma_f32 %0, %1, %2, %0 op_sel:[0,1,0] op_sel_hi:[1,1,1]" : "+v"(d) : "v"(a), "v"(b))
#define PKADD(d,a,b)    asm("v_pk_add_f32 %0, %1, %2" : "=v"(d) : "v"(a), "v"(b))

// sigmoid with -L2E pre-folded into weights:  a = -L2E*x -> 1/(1+2^a)
__device__ __forceinline__ float sig_pre(float a) {
    return __builtin_amdgcn_rcpf(1.0f + __builtin_amdgcn_exp2f(a));
}
// tanh with +2*L2E pre-folded:  a = 2*L2E*x -> tanh(x) = 1 - 2/(1+2^a)
__device__ __forceinline__ float tanh_pre(float a) {
    return fmaf(-2.0f, __builtin_amdgcn_rcpf(1.0f + __builtin_amdgcn_exp2f(a)), 1.0f);
}

extern "C" __global__ void __launch_bounds__(64)
__attribute__((amdgpu_waves_per_eu(1, 1)))
lstm_dpp8v10(const float* __restrict__ x,
             const float* __restrict__ wih0, const float* __restrict__ whh0,
             const float* __restrict__ bih0, const float* __restrict__ bhh0,
             const float* __restrict__ wih1, const float* __restrict__ whh1,
             const float* __restrict__ bih1, const float* __restrict__ bhh1,
             const float* __restrict__ fc1w, const float* __restrict__ fc1b,
             const float* __restrict__ fc2w, const float* __restrict__ fc2b,
             float* __restrict__ out, int nbatch)
{
    const int L   = threadIdx.x;                 // 0..63
    const int l   = L & 15;
    const int row = L >> 4;                      // 0..3
    const int cst = (l >> 2) & 1;                // coset within row
    const int p   = (l & 3) | ((l >> 3) << 2);   // position in coset, 0..7
    const bool lowq = ((L >> 3) & 1) == 0;       // lane in units-0..3 quad

    int seq = blockIdx.x * 8 + row * 2 + cst;
    const bool live = (seq < nbatch);
    if (!live) seq = nbatch - 1;

    const float km = (p < 6) ? 1.0f : 0.0f;      // pad lanes 6,7
    const int   k  = (p < 6) ? p : 0;
    const int ir = k, fr = 6 + k, gr = 12 + k, orr = 18 + k;  // i,f,g,o rows

    // ---- weights. Gate pairs A=[i,f] (sigmoid,-L2E | sigmoid,-L2E),
    //               B=[g,o] (tanh,+2L2E | sigmoid,-L2E). Unit-ordered slots.
    v2f wiA0[6], wiB0[6];
    v2f whA0[6], whB0[6], wiA1[6], wiB1[6], whA1[6], whB1[6], f1wA[6], f1wB[6];
#pragma unroll
    for (int j = 0; j < 6; ++j) {
        wiA0[j] = (v2f){ wih0[ir*6+j]*(-L2E)*km,  wih0[fr*6+j]*(-L2E)*km };
        wiB0[j] = (v2f){ wih0[gr*6+j]*( TL2E)*km, wih0[orr*6+j]*(-L2E)*km };
        whA0[j] = (v2f){ whh0[ir*6+j]*(-L2E)*km,  whh0[fr*6+j]*(-L2E)*km };
        whB0[j] = (v2f){ whh0[gr*6+j]*( TL2E)*km, whh0[orr*6+j]*(-L2E)*km };
        wiA1[j] = (v2f){ wih1[ir*6+j]*(-L2E)*km,  wih1[fr*6+j]*(-L2E)*km };
        wiB1[j] = (v2f){ wih1[gr*6+j]*( TL2E)*km, wih1[orr*6+j]*(-L2E)*km };
        whA1[j] = (v2f){ whh1[ir*6+j]*(-L2E)*km,  whh1[fr*6+j]*(-L2E)*km };
        whB1[j] = (v2f){ whh1[gr*6+j]*( TL2E)*km, whh1[orr*6+j]*(-L2E)*km };
        f1wA[j] = (v2f){ fc1w[(4*p+0)*6+j], fc1w[(4*p+1)*6+j] };
        f1wB[j] = (v2f){ fc1w[(4*p+2)*6+j], fc1w[(4*p+3)*6+j] };
    }
    v2f bbA0 = (v2f){ (bih0[ir]+bhh0[ir])*(-L2E)*km,  (bih0[fr]+bhh0[fr])*(-L2E)*km };
    v2f bbB0 = (v2f){ (bih0[gr]+bhh0[gr])*( TL2E)*km, (bih0[orr]+bhh0[orr])*(-L2E)*km };
    v2f bbA1 = (v2f){ (bih1[ir]+bhh1[ir])*(-L2E)*km,  (bih1[fr]+bhh1[fr])*(-L2E)*km };
    v2f bbB1 = (v2f){ (bih1[gr]+bhh1[gr])*( TL2E)*km, (bih1[orr]+bhh1[orr])*(-L2E)*km };
    v2f f1bA = (v2f){ fc1b[4*p+0], fc1b[4*p+1] };
    v2f f1bB = (v2f){ fc1b[4*p+2], fc1b[4*p+3] };
    v2f f2wA = (v2f){ fc2w[4*p+0], fc2w[4*p+1] };
    v2f f2wB = (v2f){ fc2w[4*p+2], fc2w[4*p+3] };
    float f2b = fc2b[0];

#pragma unroll
    for (int j = 0; j < 6; ++j) {
        PIN(wiA0[j]); PIN(wiB0[j]); PIN(whA0[j]); PIN(whB0[j]);
        PIN(wiA1[j]); PIN(wiB1[j]); PIN(whA1[j]); PIN(whB1[j]);
        PIN(f1wA[j]); PIN(f1wB[j]);
    }
    PIN(bbA0); PIN(bbB0); PIN(bbA1); PIN(bbB1);
    PIN(f1bA); PIN(f1bB); PIN(f2wA); PIN(f2wB); PIN(f2b);

    // ---- state: h packed pairwise, units (0,1),(2,3),(4,5)
    v2f h0p[3], h1p[3];
    const v2f Z2 = (v2f){0.0f, 0.0f};
#pragma unroll
    for (int q = 0; q < 3; ++q) { h0p[q] = Z2; h1p[q] = Z2; }
    float c0 = 0.0f, c1 = 0.0f;

    const float* xp = x + (size_t)seq * (512 * 6);
    float*       op = out + (size_t)seq * 512;

    // ---- 4-deep x prefetch, pairs (x0,x1),(x2,x3),(x4,x5) as v2f
    v2f xq[4][3];
#pragma unroll
    for (int j = 0; j < 4; ++j) {
        const float* q = xp + j * 6;
        xq[j][0] = *(const v2f*)(q + 0);
        xq[j][1] = *(const v2f*)(q + 2);
        xq[j][2] = *(const v2f*)(q + 4);
    }

    // unit-ordered gather: h[unit j] -> slot j on every lane, 6 slots
#define GATHER(HP_, HV_)                                                        \
    {                                                                           \
        float u_ = dppf<DPP_X8>(HV_);            /* partner quad's h */         \
        float hl = lowq ? (HV_) : u_;            /* units 0-3 @ quad pos */     \
        float hh = lowq ? u_ : (HV_);            /* units 4-7 @ quad pos */     \
        HP_[0] = (v2f){ dppf<DPP_B0>(hl), dppf<DPP_B1>(hl) };                   \
        HP_[1] = (v2f){ dppf<DPP_B2>(hl), dppf<DPP_B3>(hl) };                   \
        HP_[2] = (v2f){ dppf<DPP_B0>(hh), dppf<DPP_B1>(hh) };                   \
    }

    // ---- cell0 FULL gate-preactivation accumulators for the CURRENT step.
    // Hold bias + x-part + wh-part. For t=0 the wh-part is zero (h0p = 0), so
    // the prologue computes bias + x-part only -> identical arithmetic.
    v2f xgA, xgA2, xgB, xgB2;
    {
        xgA = bbA0; xgA2 = Z2; xgB = bbB0; xgB2 = Z2;
        PKFMA_LO(xgA, wiA0[0], xq[0][0]); PKFMA_HI(xgA2, wiA0[1], xq[0][0]);
        PKFMA_LO(xgA, wiA0[2], xq[0][1]); PKFMA_HI(xgA2, wiA0[3], xq[0][1]);
        PKFMA_LO(xgA, wiA0[4], xq[0][2]); PKFMA_HI(xgA2, wiA0[5], xq[0][2]);
        PKFMA_LO(xgB, wiB0[0], xq[0][0]); PKFMA_HI(xgB2, wiB0[1], xq[0][0]);
        PKFMA_LO(xgB, wiB0[2], xq[0][1]); PKFMA_HI(xgB2, wiB0[3], xq[0][1]);
        PKFMA_LO(xgB, wiB0[4], xq[0][2]); PKFMA_HI(xgB2, wiB0[5], xq[0][2]);
    }

    float y[4];

    for (int T = 0; T < 512; T += 4) {
        const int Tn = (T < 508) ? T + 4 : 508;   // clamped prefetch base
#pragma unroll
        for (int j = 0; j < 4; ++j) {
            // -- issue x[T+j+4] loads early (consumed next outer iter)
            const float* xr = xp + (Tn + j) * 6;
            v2f nx0 = *(const v2f*)(xr + 0);
            v2f nx1 = *(const v2f*)(xr + 2);
            v2f nx2 = *(const v2f*)(xr + 4);

            // -- gates0 close IMMEDIATELY (xg* already holds bias+x+wh parts)
            v2f gA0, gB0;
            PKADD(gA0, xgA, xgA2);
            PKADD(gB0, xgB, xgB2);

            float i0 = sig_pre(gA0.x), f0 = sig_pre(gA0.y);
            float g0 = tanh_pre(gB0.x), o0 = sig_pre(gB0.y);

            // -- act0-window filler 1: cell1 recurrent partial (h1p(t-1))
            v2f pA = bbA1, pA2 = Z2, pB = bbB1, pB2 = Z2;
            PKFMA_LO(pA, whA1[0], h1p[0]); PKFMA_HI(pA2, whA1[1], h1p[0]);
            PKFMA_LO(pA, whA1[2], h1p[1]); PKFMA_HI(pA2, whA1[3], h1p[1]);
            PKFMA_LO(pA, whA1[4], h1p[2]); PKFMA_HI(pA2, whA1[5], h1p[2]);
            PKFMA_LO(pB, whB1[0], h1p[0]); PKFMA_HI(pB2, whB1[1], h1p[0]);
            PKFMA_LO(pB, whB1[2], h1p[1]); PKFMA_HI(pB2, whB1[3], h1p[1]);
            PKFMA_LO(pB, whB1[4], h1p[2]); PKFMA_HI(pB2, whB1[5], h1p[2]);

            // -- act0-window filler 2: x-part of gates0(t+1) into fresh regs
            {
                const v2f* xn = xq[(j + 1) & 3];
                v2f tA = bbA0, tA2 = Z2, tB = bbB0, tB2 = Z2;
                PKFMA_LO(tA, wiA0[0], xn[0]); PKFMA_HI(tA2, wiA0[1], xn[0]);
                PKFMA_LO(tA, wiA0[2], xn[1]); PKFMA_HI(tA2, wiA0[3], xn[1]);
                PKFMA_LO(tA, wiA0[4], xn[2]); PKFMA_HI(tA2, wiA0[5], xn[2]);
                PKFMA_LO(tB, wiB0[0], xn[0]); PKFMA_HI(tB2, wiB0[1], xn[0]);
                PKFMA_LO(tB, wiB0[2], xn[1]); PKFMA_HI(tB2, wiB0[3], xn[1]);
                PKFMA_LO(tB, wiB0[4], xn[2]); PKFMA_HI(tB2, wiB0[5], xn[2]);
                xgA = tA; xgA2 = tA2; xgB = tB; xgB2 = tB2;
            }

            c0 = fmaf(f0, c0, i0 * g0);
            float h0 = o0 * tanh_pre(TL2E * c0);

            GATHER(h0p, h0);

            // -- cell 1 finish (input part over fresh h0)
            PKFMA_LO(pA, wiA1[0], h0p[0]); PKFMA_HI(pA2, wiA1[1], h0p[0]);
            PKFMA_LO(pA, wiA1[2], h0p[1]); PKFMA_HI(pA2, wiA1[3], h0p[1]);
            PKFMA_LO(pA, wiA1[4], h0p[2]); PKFMA_HI(pA2, wiA1[5], h0p[2]);
            PKFMA_LO(pB, wiB1[0], h0p[0]); PKFMA_HI(pB2, wiB1[1], h0p[0]);
            PKFMA_LO(pB, wiB1[2], h0p[1]); PKFMA_HI(pB2, wiB1[3], h0p[1]);
            PKFMA_LO(pB, wiB1[4], h0p[2]); PKFMA_HI(pB2, wiB1[5], h0p[2]);
            v2f gA1, gB1;
            PKADD(gA1, pA, pA2);
            PKADD(gB1, pB, pB2);

            float i1 = sig_pre(gA1.x), f1 = sig_pre(gA1.y);
            float g1 = tanh_pre(gB1.x), o1 = sig_pre(gB1.y);

            // -- act1-window filler (THE v10 change): wh-part of gates0(t+1).
            //    h0p already holds h0(t); accumulate into xg* so step t+1
            //    opens with just 2 pk_adds. Same per-accumulator order as v9.
            PKFMA_LO(xgA, whA0[0], h0p[0]);  PKFMA_HI(xgA2, whA0[1], h0p[0]);
            PKFMA_LO(xgA, whA0[2], h0p[1]);  PKFMA_HI(xgA2, whA0[3], h0p[1]);
            PKFMA_LO(xgA, whA0[4], h0p[2]);  PKFMA_HI(xgA2, whA0[5], h0p[2]);
            PKFMA_LO(xgB, whB0[0], h0p[0]);  PKFMA_HI(xgB2, whB0[1], h0p[0]);
            PKFMA_LO(xgB, whB0[2], h0p[1]);  PKFMA_HI(xgB2, whB0[3], h0p[1]);
            PKFMA_LO(xgB, whB0[4], h0p[2]);  PKFMA_HI(xgB2, whB0[5], h0p[2]);

            c1 = fmaf(f1, c1, i1 * g1);
            float h1 = o1 * tanh_pre(TL2E * c1);

            GATHER(h1p, h1);

            // -- FC head on fresh h1 (independent of next step's recurrence;
            //    overlaps next step's act0 in the unrolled stream)
            v2f rA = f1bA, rA2 = Z2, rB = f1bB, rB2 = Z2;
            PKFMA_LO(rA, f1wA[0], h1p[0]); PKFMA_HI(rA2, f1wA[1], h1p[0]);
            PKFMA_LO(rA, f1wA[2], h1p[1]); PKFMA_HI(rA2, f1wA[3], h1p[1]);
            PKFMA_LO(rA, f1wA[4], h1p[2]); PKFMA_HI(rA2, f1wA[5], h1p[2]);
            PKFMA_LO(rB, f1wB[0], h1p[0]); PKFMA_HI(rB2, f1wB[1], h1p[0]);
            PKFMA_LO(rB, f1wB[2], h1p[1]); PKFMA_HI(rB2, f1wB[3], h1p[1]);
            PKFMA_LO(rB, f1wB[4], h1p[2]); PKFMA_HI(rB2, f1wB[5], h1p[2]);
            v2f RA, RB;
            PKADD(RA, rA, rA2);
            PKADD(RB, rB, rB2);
            float acc =          fmaxf(RA.x, 0.0f) * f2wA.x;
            acc = fmaf(fmaxf(RA.y, 0.0f), f2wA.y, acc);
            acc = fmaf(fmaxf(RB.x, 0.0f), f2wB.x, acc);
            acc = fmaf(fmaxf(RB.y, 0.0f), f2wB.y, acc);
            // butterfly reduce over the 8-lane coset (pure VALU)
            acc += dppf<DPP_X1>(acc);
            acc += dppf<DPP_X2>(acc);
            acc += dppf<DPP_X8>(acc);
            y[j] = fmaxf(acc + f2b, 0.0f);

            // -- rotate x prefetch
            xq[j][0] = nx0; xq[j][1] = nx1; xq[j][2] = nx2;
        }
        // -- one coalesced 16B out-store per 4 steps (lane p==0 of each coset)
        if (live && ((L & 11) == 0)) {
            float4 yv = make_float4(y[0], y[1], y[2], y[3]);
            *(float4*)(op + T) = yv;
        }
    }
}

extern "C" void kernel_launch(void* const* d_in, const int* in_sizes, int n_in,
                              void* d_out, int out_size, void* d_ws, size_t ws_size,
                              hipStream_t stream) {
    const float* x     = (const float*)d_in[0];
    const float* wih0  = (const float*)d_in[1];
    const float* whh0  = (const float*)d_in[2];
    const float* bih0  = (const float*)d_in[3];
    const float* bhh0  = (const float*)d_in[4];
    const float* wih1  = (const float*)d_in[5];
    const float* whh1  = (const float*)d_in[6];
    const float* bih1  = (const float*)d_in[7];
    const float* bhh1  = (const float*)d_in[8];
    const float* fc1w  = (const float*)d_in[9];
    const float* fc1b  = (const float*)d_in[10];
    const float* fc2w  = (const float*)d_in[11];
    const float* fc2b  = (const float*)d_in[12];
    float* out = (float*)d_out;

    const int nbatch = in_sizes[0] / (512 * 6);     // 8192
    const int grid   = (nbatch + 7) / 8;            // 8 seqs per 64-thread wave

    hipLaunchKernelGGL(lstm_dpp8v10, dim3(grid), dim3(64), 0, stream,
                       x, wih0, whh0, bih0, bhh0, wih1, whh1, bih1, bhh1,
                       fc1w, fc1b, fc2w, fc2b, out, nbatch);
}